// Round 5
// baseline (625.495 us; speedup 1.0000x reference)
//
#include <hip/hip_runtime.h>

#define D 64
#define NCHUNK 256          // partition chunks (= blocks in P1/P3)
#define BSHIFT 7            // 128 nodes per bucket
#define BNODES 128
#define MAXBUK 1024         // static LDS arrays; nBuckets = 782 for N=100k

// ---------------------------------------------------------------------------
// Bucketed-partition pipeline. R4's k_fill wrote 84 MB HBM for a 4.8 MB eidx
// (random 4B scatter + cross-XCD cursor atomics -> 64B line churn). Here:
//   P1 per-chunk LDS histogram over 782 buckets
//   scan (3 kernels) over the 782x256 count matrix, bucket-major
//   P3 bucketed write of packed 4B records (src | dstLocal<<20)
//   P4 one block per bucket: ds_add_f32 into a 32KB LDS slice, no global
//      atomics; mean written to d_out (hmean scratch)
//   transform: proven register-W kernel, in-place on d_out
// ---------------------------------------------------------------------------

__global__ __launch_bounds__(256) void p1_count(
    const int* __restrict__ dst, int* __restrict__ counts,
    int nEdges, int nBuckets, int chunk)
{
    __shared__ int cnt[MAXBUK];
    const int t = threadIdx.x;
    for (int i = t; i < nBuckets; i += 256) cnt[i] = 0;
    __syncthreads();
    const int beg = blockIdx.x * chunk;
    const int end = min(beg + chunk, nEdges);
    for (int i = beg + t; i < end; i += 256)
        atomicAdd(&cnt[dst[i] >> BSHIFT], 1);            // LDS atomics
    __syncthreads();
    for (int i = t; i < nBuckets; i += 256)
        counts[i * NCHUNK + blockIdx.x] = cnt[i];        // bucket-major
}

// per-block exclusive scan (in-place safe: reads A[g] before writing)
__global__ __launch_bounds__(1024) void k_scan1(
    int* __restrict__ A, int* __restrict__ bsum, int n)
{
    __shared__ int s[1024];
    const int t = threadIdx.x;
    const int g = blockIdx.x * 1024 + t;
    const int v = (g < n) ? A[g] : 0;
    s[t] = v;
    __syncthreads();
    for (int off = 1; off < 1024; off <<= 1) {
        const int u = (t >= off) ? s[t - off] : 0;
        __syncthreads();
        s[t] += u;
        __syncthreads();
    }
    if (g < n) A[g] = s[t] - v;                          // exclusive
    if (t == 1023) bsum[blockIdx.x] = s[t];              // block total
}

__global__ __launch_bounds__(256) void k_scan2(int* __restrict__ bsum, int nb)
{
    __shared__ int s[256];
    const int t = threadIdx.x;
    const int v = (t < nb) ? bsum[t] : 0;
    s[t] = v;
    __syncthreads();
    for (int off = 1; off < 256; off <<= 1) {
        const int u = (t >= off) ? s[t - off] : 0;
        __syncthreads();
        s[t] += u;
        __syncthreads();
    }
    if (t < nb) bsum[t] = s[t] - v;
}

__global__ __launch_bounds__(256) void k_scan3(
    int* __restrict__ A, const int* __restrict__ bsum, int n, int e)
{
    const int g = blockIdx.x * blockDim.x + threadIdx.x;
    if (g < n) A[g] += bsum[g >> 10];
    if (g == 0) A[n] = e;
}

__global__ __launch_bounds__(256) void p3_partition(
    const int* __restrict__ src, const int* __restrict__ dst,
    const int* __restrict__ offsets, int* __restrict__ edata,
    int nEdges, int nBuckets, int chunk)
{
    __shared__ int cur[MAXBUK];
    const int t = threadIdx.x;
    for (int i = t; i < nBuckets; i += 256)
        cur[i] = offsets[i * NCHUNK + blockIdx.x];
    __syncthreads();
    const int beg = blockIdx.x * chunk;
    const int end = min(beg + chunk, nEdges);
    for (int i = beg + t; i < end; i += 256) {
        const int dv = dst[i];
        const int b  = dv >> BSHIFT;
        const int p  = atomicAdd(&cur[b], 1);            // LDS atomic
        edata[p] = src[i] | ((dv & (BNODES - 1)) << 20); // packed 4B record
    }
}

// one block per bucket: accumulate 128x64 f32 slice + deg in LDS, write mean
__global__ __launch_bounds__(256) void p4_agg(
    const float* __restrict__ feat, const int* __restrict__ offsets,
    const int* __restrict__ edata, float* __restrict__ hmean,
    int nBuckets, int nNodes)
{
    __shared__ float slice[BNODES][D];   // row*256B: lane-consecutive, 2/bank
    __shared__ int   degL[BNODES];
    const int t = threadIdx.x, lane = t & 63, wave = t >> 6;
    const int b = blockIdx.x;

    for (int i = t; i < BNODES * D; i += 256) ((float*)slice)[i] = 0.f;
    for (int i = t; i < BNODES; i += 256) degL[i] = 0;
    __syncthreads();

    const int beg = offsets[b * NCHUNK];
    const int end = offsets[(b + 1) * NCHUNK];   // valid: A[n]=nEdges sentinel
                                                  // covers b == nBuckets-1
    for (int base = beg + wave * 64; base < end; base += 256) {
        const int m  = min(64, end - base);
        const int ev = (lane < m) ? edata[base + lane] : 0;   // coalesced
#pragma unroll 4
        for (int j = 0; j < m; ++j) {
            const int e  = __builtin_amdgcn_readlane(ev, j);
            const int s  = e & 0xFFFFF;
            const int dl = e >> 20;
            const float v = feat[(size_t)s * D + lane];       // 256B, LLC-hit
            atomicAdd(&slice[dl][lane], v);                    // ds_add_f32
            if (lane == 0) atomicAdd(&degL[dl], 1);
        }
    }
    __syncthreads();

    for (int r = wave; r < BNODES; r += 4) {
        const int node = b * BNODES + r;
        if (node < nNodes) {
            const float inv = 1.f / fmaxf((float)degL[r], 1.f);
            hmean[(size_t)node * D + lane] = slice[r][lane] * inv;
        }
    }
}

// register-W transform (proven R3/R4). Reads h from out, overwrites in place.
__global__ __launch_bounds__(256) void k_transform(
    const float* __restrict__ feat,
    const float* __restrict__ Ws, const float* __restrict__ Wn,
    const float* __restrict__ bias,
    float* out, int nNodes)
{
    const int lane = threadIdx.x & 63;
    const int wid  = (blockIdx.x * blockDim.x + threadIdx.x) >> 6;
    const int nW   = (gridDim.x * blockDim.x) >> 6;

    float ws[D], wn[D];
#pragma unroll
    for (int k = 0; k < D; ++k) {
        ws[k] = Ws[lane * D + k];
        wn[k] = Wn[lane * D + k];
    }
    const float bv = bias[lane];

    for (int n = wid; n < nNodes; n += nW) {
        const float f = feat[(size_t)n * D + lane];
        const float h = out[(size_t)n * D + lane];
        float accS = bv;
        float accN = 0.f;
#pragma unroll
        for (int k = 0; k < D; ++k) {
            const float fk = __uint_as_float(
                __builtin_amdgcn_readlane(__float_as_uint(f), k));
            const float hk = __uint_as_float(
                __builtin_amdgcn_readlane(__float_as_uint(h), k));
            accS = fmaf(fk, ws[k], accS);
            accN = fmaf(hk, wn[k], accN);
        }
        out[(size_t)n * D + lane] = accS + accN;
    }
}

// ---------------------------------------------------------------------------
extern "C" void kernel_launch(void* const* d_in, const int* in_sizes, int n_in,
                              void* d_out, int out_size, void* d_ws, size_t ws_size,
                              hipStream_t stream)
{
    const float* feat = (const float*)d_in[0];
    const int*   src  = (const int*)  d_in[1];
    const int*   dst  = (const int*)  d_in[2];
    const float* Ws   = (const float*)d_in[3];
    const float* Wn   = (const float*)d_in[4];
    const float* bias = (const float*)d_in[5];
    float*       out  = (float*)d_out;

    const int nEdges   = in_sizes[1];
    const int nNodes   = in_sizes[0] / D;
    const int nBuckets = (nNodes + BNODES - 1) >> BSHIFT;        // 782
    const int chunk    = (nEdges + NCHUNK - 1) / NCHUNK;         // 4688
    const int nMat     = nBuckets * NCHUNK;                      // 200192
    const int nSB      = (nMat + 1023) / 1024;                   // 196 (<=256)

    // ws layout (ints): offsets[nMat+1] | bsum[256] | edata[nEdges]  ~5.6 MB
    int* offsets = (int*)d_ws;
    int* bsum    = offsets + nMat + 1;
    int* edata   = bsum + 256;

    p1_count    <<<NCHUNK, 256, 0, stream>>>(dst, offsets, nEdges, nBuckets, chunk);
    k_scan1     <<<nSB, 1024, 0, stream>>>(offsets, bsum, nMat);
    k_scan2     <<<1, 256, 0, stream>>>(bsum, nSB);
    k_scan3     <<<(nMat + 255) / 256, 256, 0, stream>>>(offsets, bsum, nMat, nEdges);
    p3_partition<<<NCHUNK, 256, 0, stream>>>(src, dst, offsets, edata,
                                             nEdges, nBuckets, chunk);
    p4_agg      <<<nBuckets, 256, 0, stream>>>(feat, offsets, edata, out,
                                               nBuckets, nNodes);
    k_transform <<<2048, 256, 0, stream>>>(feat, Ws, Wn, bias, out, nNodes);
}

// Round 6
// 215.387 us; speedup vs baseline: 2.9041x; 2.9041x over previous
//
#include <hip/hip_runtime.h>

#define D 64
#define NCHUNK 256          // partition chunks (= blocks in p1/p3)
#define BSHIFT 7            // 128 nodes per bucket
#define BNODES 128
#define MAXBUK 1024         // static LDS; nBuckets = 782 for N=100k

// ---------------------------------------------------------------------------
// Pipeline (R5 post-mortem: bucket-LDS aggregation was latency-bound at 782
// blocks; revert to R4's CSR gather which ran <93us at 8192 waves. Fix R4's
// k_fill (93us, 84MB writes for 4.8MB) with a two-level fill: cheap bucketed
// partition of packed records, then per-bucket CSR scatter via LDS cursors —
// writes confined to each bucket's ~6KB CSR window.)
//   1 zero deg            2 hist dst->deg          3-5 scan deg -> rowptr
//   6 p1 bucket histogram 7-9 scan counts->offsets 10 p3 partition records
//   11 fill2 records->CSR eidx   12 agg (float4, 4 edges in flight)
//   13 transform (register-W, in-place on d_out)
// ---------------------------------------------------------------------------

__global__ __launch_bounds__(256) void k_zero_i32(int* __restrict__ p, int n)
{
    int i = blockIdx.x * blockDim.x + threadIdx.x;
    const int st = gridDim.x * blockDim.x;
    for (; i < n; i += st) p[i] = 0;
}

__global__ __launch_bounds__(256) void k_hist(
    const int* __restrict__ dst, int* __restrict__ deg, int e)
{
    int i = blockIdx.x * blockDim.x + threadIdx.x;
    const int st = gridDim.x * blockDim.x;
    for (; i < e; i += st) atomicAdd(&deg[dst[i]], 1);
}

// per-block exclusive scan, in place; block total -> bsum
__global__ __launch_bounds__(1024) void k_scan1(
    int* __restrict__ A, int* __restrict__ bsum, int n)
{
    __shared__ int s[1024];
    const int t = threadIdx.x;
    const int g = blockIdx.x * 1024 + t;
    const int v = (g < n) ? A[g] : 0;
    s[t] = v;
    __syncthreads();
    for (int off = 1; off < 1024; off <<= 1) {
        const int u = (t >= off) ? s[t - off] : 0;
        __syncthreads();
        s[t] += u;
        __syncthreads();
    }
    if (g < n) A[g] = s[t] - v;                      // exclusive
    if (t == 1023) bsum[blockIdx.x] = s[t];          // block total
}

__global__ __launch_bounds__(256) void k_scan2(int* __restrict__ bsum, int nb)
{
    __shared__ int s[256];
    const int t = threadIdx.x;
    const int v = (t < nb) ? bsum[t] : 0;
    s[t] = v;
    __syncthreads();
    for (int off = 1; off < 256; off <<= 1) {
        const int u = (t >= off) ? s[t - off] : 0;
        __syncthreads();
        s[t] += u;
        __syncthreads();
    }
    if (t < nb) bsum[t] = s[t] - v;
}

__global__ __launch_bounds__(256) void k_scan3(
    int* __restrict__ A, const int* __restrict__ bsum, int n, int e)
{
    const int g = blockIdx.x * blockDim.x + threadIdx.x;
    if (g < n) A[g] += bsum[g >> 10];
    if (g == 0) A[n] = e;                            // sentinel
}

__global__ __launch_bounds__(256) void p1_count(
    const int* __restrict__ dst, int* __restrict__ counts,
    int nEdges, int nBuckets, int chunk)
{
    __shared__ int cnt[MAXBUK];
    const int t = threadIdx.x;
    for (int i = t; i < nBuckets; i += 256) cnt[i] = 0;
    __syncthreads();
    const int beg = blockIdx.x * chunk;
    const int end = min(beg + chunk, nEdges);
    for (int i = beg + t; i < end; i += 256)
        atomicAdd(&cnt[dst[i] >> BSHIFT], 1);        // LDS atomics
    __syncthreads();
    for (int i = t; i < nBuckets; i += 256)
        counts[i * NCHUNK + blockIdx.x] = cnt[i];    // bucket-major
}

__global__ __launch_bounds__(256) void p3_partition(
    const int* __restrict__ src, const int* __restrict__ dst,
    const int* __restrict__ offsets, int* __restrict__ edata,
    int nEdges, int nBuckets, int chunk)
{
    __shared__ int cur[MAXBUK];
    const int t = threadIdx.x;
    for (int i = t; i < nBuckets; i += 256)
        cur[i] = offsets[i * NCHUNK + blockIdx.x];
    __syncthreads();
    const int beg = blockIdx.x * chunk;
    const int end = min(beg + chunk, nEdges);
    for (int i = beg + t; i < end; i += 256) {
        const int dv = dst[i];
        const int b  = dv >> BSHIFT;
        const int p  = atomicAdd(&cur[b], 1);        // LDS atomic
        edata[p] = src[i] | ((dv & (BNODES - 1)) << 20);
    }
}

// one block per bucket: scatter records into CSR slots; LDS cursors seeded
// from rowptr; all writes land in this bucket's ~6KB eidx window.
__global__ __launch_bounds__(256) void k_fill2(
    const int* __restrict__ edata, const int* __restrict__ offsets,
    const int* __restrict__ rowptr, int* __restrict__ eidx,
    int nNodes)
{
    __shared__ int curs[BNODES];
    const int b = blockIdx.x, t = threadIdx.x;
    const int nbase = b * BNODES;
    for (int r = t; r < BNODES; r += 256) {
        const int node = nbase + r;
        curs[r] = (node < nNodes) ? rowptr[node] : 0;
    }
    __syncthreads();
    const int beg = offsets[b * NCHUNK];
    const int end = offsets[(b + 1) * NCHUNK];       // sentinel covers last b
    for (int i = beg + t; i < end; i += 256) {
        const int e = edata[i];
        const int p = atomicAdd(&curs[e >> 20], 1);  // LDS atomic
        eidx[p] = e & 0xFFFFF;
    }
}

// one wave per node, 4 edges in flight: 16-lane groups each gather a full
// feat row as float4 (1KB/wave-instr); neighbor id via one bpermute/round;
// cross-group shfl_xor reduce at the end.
__global__ __launch_bounds__(256) void k_agg_mean4(
    const float* __restrict__ feat, const int* __restrict__ rowptr,
    const int* __restrict__ eidx, float* __restrict__ hmean, int nNodes)
{
    const int lane = threadIdx.x & 63;
    const int g    = lane >> 4;          // edge group 0..3
    const int cb4  = (lane & 15) * 4;    // channel block
    const int wid  = (blockIdx.x * blockDim.x + threadIdx.x) >> 6;
    const int nW   = (gridDim.x * blockDim.x) >> 6;

    for (int n = wid; n < nNodes; n += nW) {
        const int beg = rowptr[n], end = rowptr[n + 1];
        float4 acc = make_float4(0.f, 0.f, 0.f, 0.f);
        for (int base = beg; base < end; base += 64) {
            const int m  = min(64, end - base);
            const int sv = (lane < m) ? eidx[base + lane] : 0;  // coalesced
#pragma unroll 4
            for (int j = 0; j < 16; ++j) {
                if (4 * j >= m) break;                // wave-uniform exit
                const int s = __shfl(sv, 4 * j + g, 64);
                if (4 * j + g < m) {
                    const float4 v = *(const float4*)&feat[(size_t)s * D + cb4];
                    acc.x += v.x; acc.y += v.y; acc.z += v.z; acc.w += v.w;
                }
            }
        }
        // reduce across the 4 edge groups (lanes xor 16, 32)
        acc.x += __shfl_xor(acc.x, 16, 64); acc.y += __shfl_xor(acc.y, 16, 64);
        acc.z += __shfl_xor(acc.z, 16, 64); acc.w += __shfl_xor(acc.w, 16, 64);
        acc.x += __shfl_xor(acc.x, 32, 64); acc.y += __shfl_xor(acc.y, 32, 64);
        acc.z += __shfl_xor(acc.z, 32, 64); acc.w += __shfl_xor(acc.w, 32, 64);
        const float inv = 1.f / fmaxf((float)(end - beg), 1.f);
        if (lane < 16) {
            float4 r = make_float4(acc.x * inv, acc.y * inv,
                                   acc.z * inv, acc.w * inv);
            *(float4*)&hmean[(size_t)n * D + cb4] = r;
        }
    }
}

// register-W transform (proven R3/R4). Reads h from out, overwrites in place.
__global__ __launch_bounds__(256) void k_transform(
    const float* __restrict__ feat,
    const float* __restrict__ Ws, const float* __restrict__ Wn,
    const float* __restrict__ bias,
    float* out, int nNodes)
{
    const int lane = threadIdx.x & 63;
    const int wid  = (blockIdx.x * blockDim.x + threadIdx.x) >> 6;
    const int nW   = (gridDim.x * blockDim.x) >> 6;

    float ws[D], wn[D];
#pragma unroll
    for (int k = 0; k < D; ++k) {
        ws[k] = Ws[lane * D + k];
        wn[k] = Wn[lane * D + k];
    }
    const float bv = bias[lane];

    for (int n = wid; n < nNodes; n += nW) {
        const float f = feat[(size_t)n * D + lane];
        const float h = out[(size_t)n * D + lane];
        float accS = bv;
        float accN = 0.f;
#pragma unroll
        for (int k = 0; k < D; ++k) {
            const float fk = __uint_as_float(
                __builtin_amdgcn_readlane(__float_as_uint(f), k));
            const float hk = __uint_as_float(
                __builtin_amdgcn_readlane(__float_as_uint(h), k));
            accS = fmaf(fk, ws[k], accS);
            accN = fmaf(hk, wn[k], accN);
        }
        out[(size_t)n * D + lane] = accS + accN;
    }
}

// ---------------------------------------------------------------------------
extern "C" void kernel_launch(void* const* d_in, const int* in_sizes, int n_in,
                              void* d_out, int out_size, void* d_ws, size_t ws_size,
                              hipStream_t stream)
{
    const float* feat = (const float*)d_in[0];
    const int*   src  = (const int*)  d_in[1];
    const int*   dst  = (const int*)  d_in[2];
    const float* Ws   = (const float*)d_in[3];
    const float* Wn   = (const float*)d_in[4];
    const float* bias = (const float*)d_in[5];
    float*       out  = (float*)d_out;

    const int nEdges   = in_sizes[1];
    const int nNodes   = in_sizes[0] / D;                    // 100000
    const int nBuckets = (nNodes + BNODES - 1) >> BSHIFT;    // 782
    const int chunk    = (nEdges + NCHUNK - 1) / NCHUNK;     // 4688
    const int nMat     = nBuckets * NCHUNK;                  // 200192
    const int nBA      = (nNodes + 1023) / 1024;             // 98  (<=256)
    const int nBB      = (nMat + 1023) / 1024;               // 196 (<=256)

    // ws (ints): rowptr[nNodes+1] | bsumA[256] | offsets[nMat+1] | bsumB[256]
    //            | edata[nEdges] | eidx[nEdges]   ~10.8 MB
    int* rowptr  = (int*)d_ws;               // used as deg, scanned in place
    int* bsumA   = rowptr + nNodes + 1;
    int* offsets = bsumA + 256;
    int* bsumB   = offsets + nMat + 1;
    int* edata   = bsumB + 256;
    int* eidx    = edata + nEdges;

    k_zero_i32  <<<128, 256, 0, stream>>>(rowptr, nNodes + 1);
    k_hist      <<<2048, 256, 0, stream>>>(dst, rowptr, nEdges);
    k_scan1     <<<nBA, 1024, 0, stream>>>(rowptr, bsumA, nNodes);
    k_scan2     <<<1, 256, 0, stream>>>(bsumA, nBA);
    k_scan3     <<<(nNodes + 255) / 256, 256, 0, stream>>>(rowptr, bsumA,
                                                           nNodes, nEdges);
    p1_count    <<<NCHUNK, 256, 0, stream>>>(dst, offsets, nEdges, nBuckets, chunk);
    k_scan1     <<<nBB, 1024, 0, stream>>>(offsets, bsumB, nMat);
    k_scan2     <<<1, 256, 0, stream>>>(bsumB, nBB);
    k_scan3     <<<(nMat + 255) / 256, 256, 0, stream>>>(offsets, bsumB,
                                                         nMat, nEdges);
    p3_partition<<<NCHUNK, 256, 0, stream>>>(src, dst, offsets, edata,
                                             nEdges, nBuckets, chunk);
    k_fill2     <<<nBuckets, 256, 0, stream>>>(edata, offsets, rowptr, eidx,
                                               nNodes);
    k_agg_mean4 <<<2048, 256, 0, stream>>>(feat, rowptr, eidx, out, nNodes);
    k_transform <<<2048, 256, 0, stream>>>(feat, Ws, Wn, bias, out, nNodes);
}